// Round 8
// baseline (1700.426 us; speedup 1.0000x reference)
//
#include <hip/hip_runtime.h>
#include <hip/hip_bf16.h>

using bf16 = __hip_bfloat16;
typedef __attribute__((ext_vector_type(8))) short bf16x8;   // 8 bf16 (4 VGPRs)
typedef __attribute__((ext_vector_type(4))) float f32x4;    // MFMA accumulator

constexpr int NN = 200000;   // nodes
constexpr int NE = 800000;   // edges
constexpr int NG = 4000;     // graphs
constexpr int ED = 16;       // edge feature dim
constexpr float BN_EPS = 1e-5f;

// Fused-block sizing: 64-edge tiles.  Block weight < WSTEP + w_max where
// w_max = max node degree + 1 (~25 for this Poisson(4) input), so edges per
// block <= 34 + w_max <= ~60 < 64.  Clamps below are insurance.
constexpr int WSTEP = 36;
constexpr int NB    = (NE + NN + WSTEP - 1) / WSTEP;   // 27778 fused blocks
constexpr int EMAX  = 64;                              // edge-tile capacity

// ---------------- storage-type helpers (fp32 or bf16 node features) --------
__device__ __forceinline__ float  ld1(const float* p) { return *p; }
__device__ __forceinline__ float  ld1(const bf16*  p) { return __bfloat162float(*p); }
__device__ __forceinline__ float2 ld2f(const float* p) { return *(const float2*)p; }
__device__ __forceinline__ float2 ld2f(const bf16*  p) {
    union { ushort2 u; bf16 h[2]; } t;
    t.u = *(const ushort2*)p;
    return make_float2(__bfloat162float(t.h[0]), __bfloat162float(t.h[1]));
}
__device__ __forceinline__ float4 ld4(const float* p) { return *(const float4*)p; }
__device__ __forceinline__ float4 ld4(const bf16*  p) {
    union { ushort4 u; bf16 h[4]; } t;
    t.u = *(const ushort4*)p;
    return make_float4(__bfloat162float(t.h[0]), __bfloat162float(t.h[1]),
                       __bfloat162float(t.h[2]), __bfloat162float(t.h[3]));
}
__device__ __forceinline__ void st1(float* p, float v) { *p = v; }
__device__ __forceinline__ void st1(bf16*  p, float v) { *p = __float2bfloat16(v); }
__device__ __forceinline__ void st4(float* p, float4 v) { *(float4*)p = v; }
__device__ __forceinline__ void st4(bf16*  p, float4 v) {
    union { ushort4 u; bf16 h[4]; } t;
    t.h[0] = __float2bfloat16(v.x); t.h[1] = __float2bfloat16(v.y);
    t.h[2] = __float2bfloat16(v.z); t.h[3] = __float2bfloat16(v.w);
    *(ushort4*)p = t.u;
}
__device__ __forceinline__ float bfraw(unsigned short u) {
    union { unsigned short s; bf16 h; } t; t.s = u;
    return __bfloat162float(t.h);
}

// async global -> LDS, 16 B per lane (m97 pattern). LDS dest must be the
// wave-uniform chunk base; HW adds lane*16.
__device__ __forceinline__ void gld16(const void* g, void* l)
{
    __builtin_amdgcn_global_load_lds(
        (const __attribute__((address_space(1))) void*)g,
        (__attribute__((address_space(3))) void*)l, 16, 0, 0);
}

// ===========================================================================
// CSR-by-dst build (once per call; reused by all 3 conv layers)
// ===========================================================================
constexpr int SCAN_CHUNK = 1024;
constexpr int SCAN_NBLK  = (NN + SCAN_CHUNK - 1) / SCAN_CHUNK;   // 196

__global__ __launch_bounds__(256)
void k_hist(const int* __restrict__ ei, int* __restrict__ cnt)
{
    int e = blockIdx.x * 256 + threadIdx.x;
    const int stride = gridDim.x * 256;
    for (; e < NE; e += stride) atomicAdd(&cnt[ei[NE + e]], 1);
}

__global__ __launch_bounds__(256)
void k_scan_block(const int* __restrict__ cnt, int* __restrict__ bsum)
{
    __shared__ int red[256];
    const int b = blockIdx.x, t = threadIdx.x;
    const int base = b * SCAN_CHUNK + t * 4;
    int s = 0;
    #pragma unroll
    for (int k = 0; k < 4; ++k) { const int i = base + k; if (i < NN) s += cnt[i]; }
    red[t] = s; __syncthreads();
    for (int off = 128; off > 0; off >>= 1) {
        if (t < off) red[t] += red[t + off];
        __syncthreads();
    }
    if (t == 0) bsum[b] = red[0];
}

__global__ __launch_bounds__(256)
void k_scan_top(int* __restrict__ bsum, int n)
{
    __shared__ int sh[256];
    const int t = threadIdx.x;
    const int orig = (t < n) ? bsum[t] : 0;
    sh[t] = orig; __syncthreads();
    for (int off = 1; off < 256; off <<= 1) {
        const int v = (t >= off) ? sh[t - off] : 0;
        __syncthreads();
        sh[t] += v;
        __syncthreads();
    }
    if (t < n) bsum[t] = sh[t] - orig;   // exclusive
}

__global__ __launch_bounds__(256)
void k_scan_emit(const int* __restrict__ cnt, const int* __restrict__ bsum,
                 int* __restrict__ row_ptr, int* __restrict__ cursor)
{
    __shared__ int sh[256];
    const int b = blockIdx.x, t = threadIdx.x;
    const int base = b * SCAN_CHUNK + t * 4;
    int c[4]; int s = 0;
    #pragma unroll
    for (int k = 0; k < 4; ++k) {
        const int i = base + k;
        c[k] = (i < NN) ? cnt[i] : 0;    // read BEFORE aliased write below
        s += c[k];
    }
    const int orig = s;
    sh[t] = s; __syncthreads();
    for (int off = 1; off < 256; off <<= 1) {
        const int v = (t >= off) ? sh[t - off] : 0;
        __syncthreads();
        sh[t] += v;
        __syncthreads();
    }
    int run = bsum[b] + sh[t] - orig;     // exclusive prefix of this thread
    #pragma unroll
    for (int k = 0; k < 4; ++k) {
        const int i = base + k;
        if (i < NN) { row_ptr[i] = run; cursor[i] = run; run += c[k]; }
    }
    if (b == 0 && t == 0) row_ptr[NN] = NE;
}

__global__ __launch_bounds__(256)
void k_scatter(const int* __restrict__ ei, int* __restrict__ cursor,
               int* __restrict__ perm)
{
    int e = blockIdx.x * 256 + threadIdx.x;
    const int stride = gridDim.x * 256;
    for (; e < NE; e += stride) {
        const int d = ei[NE + e];
        const int p = atomicAdd(&cursor[d], 1);
        perm[p] = e;
    }
}

// Fused-block boundaries: nb[t] = first node of block t, by binary search on
// W(n) = row_ptr[n] + n with target t*(NE+NN)/NB.
__global__ __launch_bounds__(256)
void k_bounds2(const int* __restrict__ row_ptr, int* __restrict__ nb)
{
    const int t = blockIdx.x * 256 + threadIdx.x;
    if (t > NB) return;
    const long long target = (long long)t * (NE + NN) / NB;
    int lo = 0, hi = NN;
    while (lo < hi) {
        const int mid = (lo + hi) >> 1;
        const long long W = (long long)row_ptr[mid] + mid;
        if (W >= target) hi = mid; else lo = mid + 1;
    }
    nb[t] = lo;
}

// Edge features as bf16 [NE,32] in perm order, zero-padded K 16->32.
__global__ __launch_bounds__(256)
void k_gather_edges_bf(const int* __restrict__ ei, const float* __restrict__ ea,
                       const int* __restrict__ perm, int* __restrict__ src_perm,
                       bf16* __restrict__ ea_bf)
{
    const int t = blockIdx.x * 256 + threadIdx.x;    // over NE*16 (2 bf16 each)
    if (t >= NE * 16) return;
    const int idx = t >> 4, k2 = (t & 15) * 2;       // k2 in 0..30
    const int e = perm[idx];
    union { ushort2 u; bf16 h[2]; } o;
    if (k2 < ED) {
        const float2 v = *(const float2*)&ea[(size_t)e * ED + k2];
        o.h[0] = __float2bfloat16(v.x);
        o.h[1] = __float2bfloat16(v.y);
    } else {
        o.u = make_ushort2(0, 0);
    }
    *(ushort2*)&ea_bf[(size_t)idx * 32 + k2] = o.u;
    if ((t & 15) == 0) src_perm[idx] = ei[e];
}

// One-shot: W[K,N] fp32 -> Wt[N,K] bf16 (transposed for the MFMA GEMM).
__global__ __launch_bounds__(256)
void k_wt(const float* __restrict__ W, bf16* __restrict__ Wt, int K, int N)
{
    const int i = blockIdx.x * 256 + threadIdx.x;
    if (i >= K * N) return;
    const int k = i / N, n = i % N;
    Wt[(size_t)n * K + k] = __float2bfloat16(W[i]);
}

// One-shot: We[16,cin] fp32 -> Wte[cin,32] bf16, K zero-padded 16->32.
__global__ __launch_bounds__(256)
void k_wte(const float* __restrict__ We, bf16* __restrict__ Wte, int cin)
{
    const int i = blockIdx.x * 256 + threadIdx.x;    // over cin*32
    if (i >= cin * 32) return;
    const int n = i >> 5, k = i & 31;
    Wte[i] = __float2bfloat16((k < ED) ? We[k * cin + n] : 0.f);
}

// BN fold coefficients: A = g*rsqrt(var+eps), B = beta - mu*A.
// st layout: [0..255]=sum, [256..511]=sumsq, [512..767]=A, [768..1023]=B.
__global__ __launch_bounds__(256)
void k_bnab(float* __restrict__ st, const float* __restrict__ g,
            const float* __restrict__ b)
{
    const int c = threadIdx.x;
    const float inv = 1.f / (float)NN;
    const float mu  = st[c] * inv;
    const float var = st[256 + c] * inv - mu * mu;
    const float A   = g[c] * rsqrtf(var + BN_EPS);
    st[512 + c] = A;
    st[768 + c] = b[c] - mu * A;
}

// ===========================================================================
// FUSED edge-MLP + aggregation, CIN=128 (layer 0), 512 threads / 8 waves,
// 64-edge tile.  LDS ~22 KB -> 4 blocks/CU (wave-capped) = 32 waves/CU.
// Phase 1: 8 waves = 4x2 strips (16 rows x 64 cols) of the 64x128 MFMA tile.
// Phase 2: nodes strided by 8 waves; row_ptr/src staged in LDS.
// ===========================================================================
template<typename XT, bool FOLD>
__global__ __launch_bounds__(512)
void fused_agg128(const XT* __restrict__ x, const bf16* __restrict__ ea_bf,
                  const bf16* __restrict__ Wte, const float* __restrict__ be,
                  const int* __restrict__ src_perm, const int* __restrict__ row_ptr,
                  const int* __restrict__ nb, const float* __restrict__ st,
                  bf16* __restrict__ agg)
{
    constexpr int CIN  = 128;
    constexpr int MSTR = CIN + 8;                  // msg LDS row stride (bf16)
    constexpr int CPL  = 2;                        // channels per lane
    __shared__ short ea_s[EMAX * 32];              // 4 KB
    __shared__ short msg[EMAX * MSTR];             // 17.4 KB
    __shared__ int   src_lds[EMAX];
    __shared__ int   rp_lds[EMAX + 4];

    const int tid  = threadIdx.x;
    const int lane = tid & 63;
    const int wv   = tid >> 6;                     // 0..7
    const int b    = blockIdx.x;
    const int n0 = nb[b], n1 = nb[b + 1];
    if (n0 >= n1) return;
    const int e0 = row_ptr[n0];
    const int e1 = row_ptr[n1];
    int ne = e1 - e0; if (ne > EMAX) ne = EMAX;    // insurance clamp
    int nnb = n1 - n0; if (nnb > EMAX) nnb = EMAX; // insurance clamp

    const int l15  = lane & 15;
    const int quad = lane >> 4;
    const int rsub = lane >> 2;
    const int part = lane & 3;

    // ---- stage ea rows (waves 0-3, 16 rows each) ----
    if (wv < 4) {
        int r = wv * 16 + rsub;
        if (r >= ne) r = ne - 1;
        gld16(&ea_bf[(size_t)(e0 + r) * 32 + part * 8], &ea_s[wv * 512]);
    }
    // ---- stage src + row_ptr slices (contiguous; overlaps with gld16) ----
    if (tid >= 256 && tid < 320) {
        const int i = tid - 256;
        src_lds[i] = src_perm[e0 + ((i < ne) ? i : ne - 1)];
    } else if (tid >= 320 && tid < 448) {
        const int i = tid - 320;
        if (i <= nnb) rp_lds[i] = row_ptr[n0 + i];
    }

    // ---- Wte fragments + bias: wave strip (wr=16-row, wc=64-col) ----
    const int wc = (wv & 1) * 64;
    const int wr = (wv >> 1) * 16;
    bf16x8 bfr[4];
    #pragma unroll
    for (int i = 0; i < 4; ++i)
        bfr[i] = *(const bf16x8*)&Wte[(size_t)(wc + i * 16 + l15) * 32 + quad * 8];
    float bv[4];
    #pragma unroll
    for (int ni = 0; ni < 4; ++ni)
        bv[ni] = be[wc + ni * 16 + l15];

    __syncthreads();                               // ea + src + rp staged

    // ---- phase 1: MFMA edge-MLP -> msg LDS (4 MFMA per wave) ----
    {
        f32x4 acc[4];
        #pragma unroll
        for (int j = 0; j < 4; ++j)
            acc[j] = (f32x4){0.f, 0.f, 0.f, 0.f};
        const bf16x8 af = *(const bf16x8*)&ea_s[(wr + l15) * 32 + quad * 8];
        #pragma unroll
        for (int ni = 0; ni < 4; ++ni)
            acc[ni] = __builtin_amdgcn_mfma_f32_16x16x32_bf16(
                          af, bfr[ni], acc[ni], 0, 0, 0);
        const int row0 = wr + quad * 4;
        #pragma unroll
        for (int r = 0; r < 4; ++r) {
            const int row = row0 + r;
            #pragma unroll
            for (int ni = 0; ni < 4; ++ni) {
                const float v = acc[ni][r] + bv[ni];
                msg[row * MSTR + wc + ni * 16 + l15] =
                    (short)__bfloat16_as_ushort(__float2bfloat16(v));
            }
        }
    }
    __syncthreads();                               // msg ready

    // ---- phase 2: node-major aggregation, 8-wave stride ----
    const int c0 = lane * CPL;
    float Af[CPL], Bf[CPL];
    #pragma unroll
    for (int q = 0; q < CPL; ++q) {
        Af[q] = FOLD ? st[512 + c0 + q] : 1.f;
        Bf[q] = FOLD ? st[768 + c0 + q] : 0.f;
    }

    for (int ni = wv; ni < nnb; ni += 8) {
        const int node = n0 + ni;
        float acc2[CPL];
        const float2 v = ld2f(&x[(size_t)node * CIN + c0]);
        acc2[0] = fmaf(v.x, Af[0], Bf[0]);
        acc2[1] = fmaf(v.y, Af[1], Bf[1]);

        const int f0 = rp_lds[ni], f1 = rp_lds[ni + 1];
        for (int base2 = f0; base2 < f1; base2 += 8) {
            float2 xv[8]; ushort2 mv[8];
            #pragma unroll
            for (int j = 0; j < 8; ++j) {
                int idx = base2 + j; if (idx >= f1) idx = f1 - 1;
                int l = idx - e0; if (l > EMAX - 1) l = EMAX - 1;
                const int sv = src_lds[l];
                xv[j] = ld2f(&x[(size_t)sv * CIN + c0]);
                mv[j] = *(const ushort2*)&msg[l * MSTR + c0];
            }
            #pragma unroll
            for (int j = 0; j < 8; ++j) {
                if (base2 + j < f1) {
                    acc2[0] += fmaxf(fmaf(xv[j].x, Af[0], Bf[0]) + bfraw(mv[j].x), 0.f);
                    acc2[1] += fmaxf(fmaf(xv[j].y, Af[1], Bf[1]) + bfraw(mv[j].y), 0.f);
                }
            }
        }

        union { ushort2 u; bf16 h[2]; } t;
        t.h[0] = __float2bfloat16(acc2[0]);
        t.h[1] = __float2bfloat16(acc2[1]);
        *(ushort2*)&agg[(size_t)node * CIN + c0] = t.u;
    }
}

// ===========================================================================
// FUSED edge-MLP + aggregation, CIN=256 (layers 1,2): 512 threads / 8 waves,
// 64-edge tile.  LDS ~38 KB -> 4 blocks/CU = 32 waves/CU (2x round 7).
// Phase 1: 8 waves = 2x4 quadrants (32 rows x 64 cols) of 64x256 tile.
// Phase 2: nodes strided by 8 waves; row_ptr/src staged in LDS.
// ===========================================================================
template<bool FOLD>
__global__ __launch_bounds__(512)
void fused_agg256(const bf16* __restrict__ x, const bf16* __restrict__ ea_bf,
                  const bf16* __restrict__ Wte, const float* __restrict__ be,
                  const int* __restrict__ src_perm, const int* __restrict__ row_ptr,
                  const int* __restrict__ nb, const float* __restrict__ st,
                  bf16* __restrict__ agg)
{
    constexpr int CIN  = 256;
    constexpr int MSTR = CIN + 8;                  // msg LDS row stride (bf16)
    constexpr int CPL  = 4;
    __shared__ short ea_s[EMAX * 32];              // 4 KB
    __shared__ short msg[EMAX * MSTR];             // 33.8 KB
    __shared__ int   src_lds[EMAX];
    __shared__ int   rp_lds[EMAX + 4];

    const int tid  = threadIdx.x;
    const int lane = tid & 63;
    const int wv   = tid >> 6;                     // 0..7
    const int b    = blockIdx.x;
    const int n0 = nb[b], n1 = nb[b + 1];
    if (n0 >= n1) return;
    const int e0 = row_ptr[n0];
    const int e1 = row_ptr[n1];
    int ne = e1 - e0; if (ne > EMAX) ne = EMAX;    // insurance clamp
    int nnb = n1 - n0; if (nnb > EMAX) nnb = EMAX; // insurance clamp

    const int l15  = lane & 15;
    const int quad = lane >> 4;
    const int rsub = lane >> 2;
    const int part = lane & 3;

    // ---- stage ea rows (waves 0-3, 16 rows each) ----
    if (wv < 4) {
        int r = wv * 16 + rsub;
        if (r >= ne) r = ne - 1;
        gld16(&ea_bf[(size_t)(e0 + r) * 32 + part * 8], &ea_s[wv * 512]);
    }
    // ---- stage src + row_ptr slices (contiguous; overlaps with gld16) ----
    if (tid >= 256 && tid < 320) {
        const int i = tid - 256;
        src_lds[i] = src_perm[e0 + ((i < ne) ? i : ne - 1)];
    } else if (tid >= 320 && tid < 448) {
        const int i = tid - 320;
        if (i <= nnb) rp_lds[i] = row_ptr[n0 + i];
    }

    // ---- Wte fragments + bias: wave quadrant (wr=32-row, wc=64-col) ----
    const int wc = (wv & 3) * 64;
    const int wr = (wv >> 2) * 32;
    bf16x8 bfr[4];
    #pragma unroll
    for (int i = 0; i < 4; ++i)
        bfr[i] = *(const bf16x8*)&Wte[(size_t)(wc + i * 16 + l15) * 32 + quad * 8];
    float bv[4];
    #pragma unroll
    for (int ni = 0; ni < 4; ++ni)
        bv[ni] = be[wc + ni * 16 + l15];

    __syncthreads();                               // ea + src + rp staged

    // ---- phase 1: MFMA edge-MLP -> msg LDS (8 MFMA per wave) ----
    {
        f32x4 acc[2][4];
        #pragma unroll
        for (int i = 0; i < 2; ++i)
            #pragma unroll
            for (int j = 0; j < 4; ++j)
                acc[i][j] = (f32x4){0.f, 0.f, 0.f, 0.f};
        bf16x8 af[2];
        #pragma unroll
        for (int i = 0; i < 2; ++i)
            af[i] = *(const bf16x8*)&ea_s[(wr + i * 16 + l15) * 32 + quad * 8];
        #pragma unroll
        for (int mi = 0; mi < 2; ++mi)
            #pragma unroll
            for (int ni = 0; ni < 4; ++ni)
                acc[mi][ni] = __builtin_amdgcn_mfma_f32_16x16x32_bf16(
                                  af[mi], bfr[ni], acc[mi][ni], 0, 0, 0);
        #pragma unroll
        for (int mi = 0; mi < 2; ++mi) {
            const int row0 = wr + mi * 16 + quad * 4;
            #pragma unroll
            for (int r = 0; r < 4; ++r) {
                const int row = row0 + r;
                #pragma unroll
                for (int ni = 0; ni < 4; ++ni) {
                    const float v = acc[mi][ni][r] + bv[ni];
                    msg[row * MSTR + wc + ni * 16 + l15] =
                        (short)__bfloat16_as_ushort(__float2bfloat16(v));
                }
            }
        }
    }
    __syncthreads();                               // msg ready

    // ---- phase 2: node-major aggregation, 8-wave stride ----
    const int c0 = lane * CPL;
    float Af[CPL], Bf[CPL];
    #pragma unroll
    for (int q = 0; q < CPL; ++q) {
        Af[q] = FOLD ? st[512 + c0 + q] : 1.f;
        Bf[q] = FOLD ? st[768 + c0 + q] : 0.f;
    }

    for (int ni = wv; ni < nnb; ni += 8) {
        const int node = n0 + ni;
        float acc2[CPL];
        const float4 v = ld4(&x[(size_t)node * CIN + c0]);
        acc2[0] = fmaf(v.x, Af[0], Bf[0]); acc2[1] = fmaf(v.y, Af[1], Bf[1]);
        acc2[2] = fmaf(v.z, Af[2], Bf[2]); acc2[3] = fmaf(v.w, Af[3], Bf[3]);

        const int f0 = rp_lds[ni], f1 = rp_lds[ni + 1];
        for (int base2 = f0; base2 < f1; base2 += 8) {
            ushort4 xr[8]; ushort4 mv[8];
            #pragma unroll
            for (int j = 0; j < 8; ++j) {
                int idx = base2 + j; if (idx >= f1) idx = f1 - 1;
                int l = idx - e0; if (l > EMAX - 1) l = EMAX - 1;
                const int sv = src_lds[l];
                xr[j] = *(const ushort4*)&x[(size_t)sv * CIN + c0];
                mv[j] = *(const ushort4*)&msg[l * MSTR + c0];
            }
            #pragma unroll
            for (int j = 0; j < 8; ++j) {
                if (base2 + j < f1) {
                    acc2[0] += fmaxf(fmaf(bfraw(xr[j].x), Af[0], Bf[0]) + bfraw(mv[j].x), 0.f);
                    acc2[1] += fmaxf(fmaf(bfraw(xr[j].y), Af[1], Bf[1]) + bfraw(mv[j].y), 0.f);
                    acc2[2] += fmaxf(fmaf(bfraw(xr[j].z), Af[2], Bf[2]) + bfraw(mv[j].z), 0.f);
                    acc2[3] += fmaxf(fmaf(bfraw(xr[j].w), Af[3], Bf[3]) + bfraw(mv[j].w), 0.f);
                }
            }
        }

        union { ushort4 u; bf16 h[4]; } t;
        t.h[0] = __float2bfloat16(acc2[0]); t.h[1] = __float2bfloat16(acc2[1]);
        t.h[2] = __float2bfloat16(acc2[2]); t.h[3] = __float2bfloat16(acc2[3]);
        *(ushort4*)&agg[(size_t)node * CIN + c0] = t.u;
    }
}

// ===========================================================================
// Conv MFMA GEMM: C[M,256] = relu(A[M,K] @ Wt[256,K]^T + bias), bf16 out.
// m97-style global_load_lds staging (linear [128][32] LDS, 16 B/lane).
// launch_bounds (256,6): VGPR 64 <= 85 and LDS 16 KB allow 6 blocks/CU.
// STATS: per-channel sum/sumsq of post-relu output into st (quad-reduce).
// ===========================================================================
template<int K, bool STATS>
__global__ __launch_bounds__(256, 6)
void gemm_mfma(const bf16* __restrict__ A, const bf16* __restrict__ Wt,
               const float* __restrict__ bias, bf16* __restrict__ C, int M,
               float* __restrict__ st)
{
    __shared__ short As[128 * 32];   // 8 KB, linear
    __shared__ short Bs[128 * 32];
    const int tid  = threadIdx.x;
    const int bm   = blockIdx.y * 128;
    const int bn   = blockIdx.x * 128;      // 0 or 128 (N = 256)
    const int lane = tid & 63;
    const int wave = tid >> 6;
    const int wr   = (wave >> 1) * 64;
    const int wc   = (wave & 1) * 64;
    const int l15  = lane & 15;
    const int quad = lane >> 4;
    const int rsub = lane >> 2;
    const int part = lane & 3;

    f32x4 acc[4][4];
    #pragma unroll
    for (int i = 0; i < 4; ++i)
        #pragma unroll
        for (int j = 0; j < 4; ++j)
            acc[i][j] = (f32x4){0.f, 0.f, 0.f, 0.f};

    for (int k0 = 0; k0 < K; k0 += 32) {
        #pragma unroll
        for (int i = 0; i < 2; ++i) {
            const int ca = wave * 2 + i;
            int ar = bm + ca * 16 + rsub; if (ar >= M) ar = M - 1;
            gld16(&A[(size_t)ar * K + k0 + part * 8], &As[ca * 512]);
            gld16(&Wt[(size_t)(bn + ca * 16 + rsub) * K + k0 + part * 8],
                  &Bs[ca * 512]);
        }
        __syncthreads();

        bf16x8 af[4], bfr[4];
        #pragma unroll
        for (int i = 0; i < 4; ++i) {
            af[i]  = *(const bf16x8*)&As[(wr + i * 16 + l15) * 32 + quad * 8];
            bfr[i] = *(const bf16x8*)&Bs[(wc + i * 16 + l15) * 32 + quad * 8];
        }
        #pragma unroll
        for (int mi = 0; mi < 4; ++mi)
            #pragma unroll
            for (int ni = 0; ni < 4; ++ni)
                acc[mi][ni] = __builtin_amdgcn_mfma_f32_16x16x32_bf16(
                                  af[mi], bfr[ni], acc[mi][ni], 0, 0, 0);
        __syncthreads();
    }

    float bv[4];
    #pragma unroll
    for (int ni = 0; ni < 4; ++ni)
        bv[ni] = bias[bn + wc + ni * 16 + l15];
    float ps[4]  = {0.f, 0.f, 0.f, 0.f};
    float ps2[4] = {0.f, 0.f, 0.f, 0.f};
    #pragma unroll
    for (int mi = 0; mi < 4; ++mi) {
        const int row0 = bm + wr + mi * 16 + quad * 4;
        #pragma unroll
        for (int r = 0; r < 4; ++r) {
            const int row = row0 + r;
            if (row < M) {
                #pragma unroll
                for (int ni = 0; ni < 4; ++ni) {
                    float v = acc[mi][ni][r] + bv[ni];
                    v = fmaxf(v, 0.f);
                    C[(size_t)row * 256 + bn + wc + ni * 16 + l15] = __float2bfloat16(v);
                    if (STATS) { ps[ni] += v; ps2[ni] = fmaf(v, v, ps2[ni]); }
                }
            }
        }
    }
    if (STATS) {
        #pragma unroll
        for (int ni = 0; ni < 4; ++ni) {
            float s = ps[ni], q = ps2[ni];
            s += __shfl_xor(s, 16); s += __shfl_xor(s, 32);
            q += __shfl_xor(q, 16); q += __shfl_xor(q, 32);
            if (quad == 0) {
                const int col = bn + wc + ni * 16 + l15;
                atomicAdd(&st[col], s);
                atomicAdd(&st[256 + col], q);
            }
        }
    }
}

// ---------------------------------------------------------------------------
// fp32 GEMM (dense head only): C = (relu?)(A @ W + bias)
// ---------------------------------------------------------------------------
template<bool RELU, typename InT, typename OutT>
__global__ __launch_bounds__(256)
void gemm_rk(const InT* __restrict__ A, const float* __restrict__ W,
             const float* __restrict__ bias, OutT* __restrict__ C,
             int M, int N, int K)
{
    __shared__ float Asm[16][64];
    __shared__ float Wsm[16][64];
    const int bm = blockIdx.y * 64;
    const int bn = blockIdx.x * 64;
    const int tid = threadIdx.x;
    const int tx = tid & 15, ty = tid >> 4;
    const int ar = tid >> 2, ac = (tid & 3) * 4;
    const int wrr = tid >> 4, wcc = (tid & 15) * 4;

    float acc[4][4] = {};

    for (int k0 = 0; k0 < K; k0 += 16) {
        float4 av = make_float4(0.f, 0.f, 0.f, 0.f);
        if (bm + ar < M)
            av = ld4(A + (size_t)(bm + ar) * K + k0 + ac);
        Asm[ac + 0][ar] = av.x; Asm[ac + 1][ar] = av.y;
        Asm[ac + 2][ar] = av.z; Asm[ac + 3][ar] = av.w;

        float4 wv = make_float4(0.f, 0.f, 0.f, 0.f);
        if (bn + wcc < N)
            wv = *(const float4*)(W + (size_t)(k0 + wrr) * N + bn + wcc);
        *(float4*)&Wsm[wrr][wcc] = wv;
        __syncthreads();

        #pragma unroll
        for (int k = 0; k < 16; ++k) {
            const float4 a4 = *(const float4*)&Asm[k][ty * 4];
            const float4 b4 = *(const float4*)&Wsm[k][tx * 4];
            const float aa[4] = {a4.x, a4.y, a4.z, a4.w};
            const float bb[4] = {b4.x, b4.y, b4.z, b4.w};
            #pragma unroll
            for (int i = 0; i < 4; ++i)
                #pragma unroll
                for (int j = 0; j < 4; ++j)
                    acc[i][j] += aa[i] * bb[j];
        }
        __syncthreads();
    }

    float bvals[4];
    #pragma unroll
    for (int j = 0; j < 4; ++j) {
        const int col = bn + tx * 4 + j;
        bvals[j] = (col < N) ? bias[col] : 0.f;
    }
    #pragma unroll
    for (int i = 0; i < 4; ++i) {
        const int row = bm + ty * 4 + i;
        if (row >= M) continue;
        float v[4];
        #pragma unroll
        for (int j = 0; j < 4; ++j) {
            v[j] = acc[i][j] + bvals[j];
            if (RELU) v[j] = fmaxf(v[j], 0.f);
        }
        if (bn + tx * 4 + 3 < N) {
            st4(C + (size_t)row * N + bn + tx * 4, make_float4(v[0], v[1], v[2], v[3]));
        } else {
            #pragma unroll
            for (int j = 0; j < 4; ++j) {
                const int col = bn + tx * 4 + j;
                if (col < N) st1(C + (size_t)row * N + col, v[j]);
            }
        }
    }
}

// ---------------------------------------------------------------------------
// Mean-pool over sorted batch ids, with BN fold applied on the fly.
// ---------------------------------------------------------------------------
template<typename InT, bool FOLD>
__global__ __launch_bounds__(256)
void pool_sum(const InT* __restrict__ h, const int* __restrict__ batch,
              const float* __restrict__ st,
              float* __restrict__ sums, float* __restrict__ cnts)
{
    const int c = threadIdx.x;
    size_t n0 = (size_t)blockIdx.x * 128;
    size_t n1 = n0 + 128; if (n1 > (size_t)NN) n1 = NN;
    if (n0 >= (size_t)NN) return;
    const float A = FOLD ? st[512 + c] : 1.f;
    const float B = FOLD ? st[768 + c] : 0.f;
    int cur = batch[n0];
    float s = 0.f, cnt = 0.f;
    for (size_t n = n0; n < n1; ++n) {
        const int b = batch[n];
        if (b != cur) {
            atomicAdd(&sums[(size_t)cur * 256 + c], s);
            if (c == 0) atomicAdd(&cnts[cur], cnt);
            s = 0.f; cnt = 0.f; cur = b;
        }
        const float v = ld1(&h[n * 256 + c]);
        s += fmaf(v, A, B);
        cnt += 1.f;
    }
    atomicAdd(&sums[(size_t)cur * 256 + c], s);
    if (c == 0) atomicAdd(&cnts[cur], cnt);
}

__global__ __launch_bounds__(256)
void pool_div(float* __restrict__ sums, const float* __restrict__ cnts)
{
    const int i = blockIdx.x * 256 + threadIdx.x;   // NG*256 threads exactly
    const int g = i >> 8;
    sums[i] = sums[i] / fmaxf(cnts[g], 1.f);
}

__global__ __launch_bounds__(256)
void head_out(const float* __restrict__ y, const float* __restrict__ Wo,
              const float* __restrict__ bo, float* __restrict__ out)
{
    const int g = blockIdx.x * 256 + threadIdx.x;
    if (g >= NG) return;
    float s = bo[0];
    #pragma unroll
    for (int k = 0; k < 32; ++k) s += y[g * 32 + k] * Wo[k];
    out[g] = s;
}

__global__ __launch_bounds__(256)
void diag_fill(float* __restrict__ out, int n, float v)
{
    const int i = blockIdx.x * 256 + threadIdx.x;
    if (i < n) out[i] = v;
}

// ---------------------------------------------------------------------------
extern "C" void kernel_launch(void* const* d_in, const int* in_sizes, int n_in,
                              void* d_out, int out_size, void* d_ws, size_t ws_size,
                              hipStream_t stream)
{
    const float* x    = (const float*)d_in[0];
    const int*   ei   = (const int*)d_in[1];
    const int*   batch= (const int*)d_in[2];
    const float* ea   = (const float*)d_in[3];
    const float* We[3] = {(const float*)d_in[4],  (const float*)d_in[10], (const float*)d_in[16]};
    const float* be[3] = {(const float*)d_in[5],  (const float*)d_in[11], (const float*)d_in[17]};
    const float* Wn[3] = {(const float*)d_in[6],  (const float*)d_in[12], (const float*)d_in[18]};
    const float* bnb[3]= {(const float*)d_in[7],  (const float*)d_in[13], (const float*)d_in[19]};
    const float* gm[3] = {(const float*)d_in[8],  (const float*)d_in[14], (const float*)d_in[20]};
    const float* bt[3] = {(const float*)d_in[9],  (const float*)d_in[15], (const float*)d_in[21]};
    const float* Wd0 = (const float*)d_in[22]; const float* bd0 = (const float*)d_in[23];
    const float* Wd1 = (const float*)d_in[24]; const float* bd1 = (const float*)d_in[25];
    const float* Wd2 = (const float*)d_in[26]; const float* bd2 = (const float*)d_in[27];
    const float* Wo  = (const float*)d_in[28]; const float* bo  = (const float*)d_in[29];
    float* out = (float*)d_out;
    float* ws  = (float*)d_ws;

    // ---- workspace layout (float offsets; 16B alignment kept) ----
    constexpr size_t OFF_H    = 0;                            // NN*256 bf16
    constexpr size_t OFF_AGG  = 25600000;                     // NN*256 bf16
    constexpr size_t OFF_ST   = 51200000;                     // 1536 fl
    constexpr size_t OFF_WT0  = OFF_ST + 1536;                // 128*256 bf16
    constexpr size_t OFF_WT1  = OFF_WT0 + 16384;              // 256*256 bf16
    constexpr size_t OFF_WT2  = OFF_WT1 + 32768;              // 256*256 bf16
    constexpr size_t OFF_WTE0 = OFF_WT2 + 32768;              // 128*32 bf16
    constexpr size_t OFF_WTE1 = OFF_WTE0 + 2048;              // 256*32 bf16
    constexpr size_t OFF_WTE2 = OFF_WTE1 + 4096;              // 256*32 bf16
    constexpr size_t OFF_EA   = OFF_WTE2 + 4096;              // NE*32 bf16
    constexpr size_t OFF_SRC  = OFF_EA + 12800000;            // NE int
    constexpr size_t OFF_RP   = OFF_SRC + NE;                 // NN+1 int
    constexpr size_t OFF_CUR  = OFF_RP + (NN + 1);            // NN int
    constexpr size_t OFF_PERM = OFF_CUR + NN;                 // NE int
    constexpr size_t OFF_BSUM = OFF_PERM + NE;                // SCAN_NBLK int
    constexpr size_t OFF_NB   = OFF_BSUM + SCAN_NBLK;         // NB+1 int
    constexpr size_t BASE_END = OFF_NB + (NB + 4);
    constexpr size_t NEED_BASE = BASE_END * 4;

    bf16*  H        = (bf16*)(ws + OFF_H);
    bf16*  AGG      = (bf16*)(ws + OFF_AGG);
    float* st       = ws + OFF_ST;
    bf16*  wt0      = (bf16*)(ws + OFF_WT0);
    bf16*  wt1      = (bf16*)(ws + OFF_WT1);
    bf16*  wt2      = (bf16*)(ws + OFF_WT2);
    bf16*  wte[3]   = {(bf16*)(ws + OFF_WTE0), (bf16*)(ws + OFF_WTE1), (bf16*)(ws + OFF_WTE2)};
    bf16*  ea_bf    = (bf16*)(ws + OFF_EA);
    int*   src_perm = (int*)(ws + OFF_SRC);
    int*   row_ptr  = (int*)(ws + OFF_RP);
    int*   cursor   = (int*)(ws + OFF_CUR);
    int*   perm     = (int*)(ws + OFF_PERM);
    int*   bsum     = (int*)(ws + OFF_BSUM);
    int*   nb       = (int*)(ws + OFF_NB);

    if (ws_size < NEED_BASE) {
        diag_fill<<<(NG + 255) / 256, 256, 0, stream>>>(out, NG, (float)(ws_size >> 20));
        return;
    }

    // ---- one-time prep: CSR build, edge pre-gather, weight transpose ----
    hipMemsetAsync(row_ptr, 0, (size_t)(NN + 1) * 4, stream);
    k_hist<<<1024, 256, 0, stream>>>(ei, row_ptr);
    k_scan_block<<<SCAN_NBLK, 256, 0, stream>>>(row_ptr, bsum);
    k_scan_top<<<1, 256, 0, stream>>>(bsum, SCAN_NBLK);
    k_scan_emit<<<SCAN_NBLK, 256, 0, stream>>>(row_ptr, bsum, row_ptr, cursor);
    k_scatter<<<1024, 256, 0, stream>>>(ei, cursor, perm);
    k_bounds2<<<(NB + 256) / 256, 256, 0, stream>>>(row_ptr, nb);
    k_gather_edges_bf<<<(NE * 16 + 255) / 256, 256, 0, stream>>>(ei, ea, perm, src_perm, ea_bf);
    k_wte<<<(128 * 32 + 255) / 256, 256, 0, stream>>>(We[0], wte[0], 128);
    k_wte<<<(256 * 32 + 255) / 256, 256, 0, stream>>>(We[1], wte[1], 256);
    k_wte<<<(256 * 32 + 255) / 256, 256, 0, stream>>>(We[2], wte[2], 256);
    k_wt<<<(128 * 256 + 255) / 256, 256, 0, stream>>>(Wn[0], wt0, 128, 256);
    k_wt<<<(256 * 256 + 255) / 256, 256, 0, stream>>>(Wn[1], wt1, 256, 256);
    k_wt<<<(256 * 256 + 255) / 256, 256, 0, stream>>>(Wn[2], wt2, 256, 256);

    const dim3 mfma_grid(2, (NN + 127) / 128);    // conv GEMMs: N=256

    // ---- layer 0 (cin=128 -> 256), input x fp32, no fold ----
    fused_agg128<float, false><<<NB, 512, 0, stream>>>(
        x, ea_bf, wte[0], be[0], src_perm, row_ptr, nb, st, AGG);
    hipMemsetAsync(st, 0, 512 * 4, stream);
    gemm_mfma<128, true><<<mfma_grid, 256, 0, stream>>>(AGG, wt0, bnb[0], H, NN, st);
    k_bnab<<<1, 256, 0, stream>>>(st, gm[0], bt[0]);

    // ---- layers 1,2 (256 -> 256), input H bf16 raw + fold(A,B) ----
    for (int l = 1; l < 3; ++l) {
        fused_agg256<true><<<NB, 512, 0, stream>>>(
            H, ea_bf, wte[l], be[l], src_perm, row_ptr, nb, st, AGG);
        hipMemsetAsync(st, 0, 512 * 4, stream);
        gemm_mfma<256, true><<<mfma_grid, 256, 0, stream>>>(
            AGG, (l == 1) ? wt1 : wt2, bnb[l], H, NN, st);
        k_bnab<<<1, 256, 0, stream>>>(st, gm[l], bt[l]);
    }

    // ---- head scratch overlays AGG (dead after last conv GEMM) ----
    float* poolb = (float*)AGG;           // NG*256 = 1,024,000 fl
    float* cnts  = poolb + 1024000;       // NG
    float* y1    = poolb + 1028000;       // NG*512
    float* y2    = poolb + 3076000;       // NG*128
    float* y3    = poolb + 3588000;       // NG*32

    hipMemsetAsync(poolb, 0, (size_t)NG * 256 * 4, stream);
    hipMemsetAsync(cnts, 0, (size_t)NG * 4, stream);
    pool_sum<bf16, true><<<(NN + 127) / 128, 256, 0, stream>>>(H, batch, st, poolb, cnts);
    pool_div<<<NG, 256, 0, stream>>>(poolb, cnts);

    // ---- dense head (fp32) ----
    gemm_rk<true, float, float><<<dim3(8, (NG + 63) / 64), 256, 0, stream>>>(poolb, Wd0, bd0, y1, NG, 512, 256);
    gemm_rk<true, float, float><<<dim3(2, (NG + 63) / 64), 256, 0, stream>>>(y1, Wd1, bd1, y2, NG, 128, 512);
    gemm_rk<true, float, float><<<dim3(1, (NG + 63) / 64), 256, 0, stream>>>(y2, Wd2, bd2, y3, NG, 32, 128);
    head_out<<<(NG + 255) / 256, 256, 0, stream>>>(y3, Wo, bo, out);
}

// Round 9
// 1344.316 us; speedup vs baseline: 1.2649x; 1.2649x over previous
//
#include <hip/hip_runtime.h>
#include <hip/hip_bf16.h>

using bf16 = __hip_bfloat16;
typedef __attribute__((ext_vector_type(8))) short bf16x8;   // 8 bf16 (4 VGPRs)
typedef __attribute__((ext_vector_type(4))) float f32x4;    // MFMA accumulator

constexpr int NN = 200000;   // nodes
constexpr int NE = 800000;   // edges
constexpr int NG = 4000;     // graphs
constexpr int ED = 16;       // edge feature dim
constexpr float BN_EPS = 1e-5f;

// Fused-block sizing: 64-edge tiles.  Block weight < WSTEP + w_max where
// w_max = max node degree + 1 (~25 for this Poisson(4) input), so edges per
// block <= 34 + w_max <= ~60 < 64.  Clamps below are insurance.
constexpr int WSTEP = 36;
constexpr int NB    = (NE + NN + WSTEP - 1) / WSTEP;   // 27778 fused blocks
constexpr int EMAX  = 64;                              // edge-tile capacity

// ---------------- storage-type helpers (fp32 or bf16 node features) --------
__device__ __forceinline__ float  ld1(const float* p) { return *p; }
__device__ __forceinline__ float  ld1(const bf16*  p) { return __bfloat162float(*p); }
__device__ __forceinline__ float2 ld2f(const float* p) { return *(const float2*)p; }
__device__ __forceinline__ float2 ld2f(const bf16*  p) {
    union { ushort2 u; bf16 h[2]; } t;
    t.u = *(const ushort2*)p;
    return make_float2(__bfloat162float(t.h[0]), __bfloat162float(t.h[1]));
}
__device__ __forceinline__ float4 ld4(const float* p) { return *(const float4*)p; }
__device__ __forceinline__ float4 ld4(const bf16*  p) {
    union { ushort4 u; bf16 h[4]; } t;
    t.u = *(const ushort4*)p;
    return make_float4(__bfloat162float(t.h[0]), __bfloat162float(t.h[1]),
                       __bfloat162float(t.h[2]), __bfloat162float(t.h[3]));
}
__device__ __forceinline__ void st1(float* p, float v) { *p = v; }
__device__ __forceinline__ void st1(bf16*  p, float v) { *p = __float2bfloat16(v); }
__device__ __forceinline__ void st4(float* p, float4 v) { *(float4*)p = v; }
__device__ __forceinline__ void st4(bf16*  p, float4 v) {
    union { ushort4 u; bf16 h[4]; } t;
    t.h[0] = __float2bfloat16(v.x); t.h[1] = __float2bfloat16(v.y);
    t.h[2] = __float2bfloat16(v.z); t.h[3] = __float2bfloat16(v.w);
    *(ushort4*)p = t.u;
}
__device__ __forceinline__ float bfraw(unsigned short u) {
    union { unsigned short s; bf16 h; } t; t.s = u;
    return __bfloat162float(t.h);
}

// async global -> LDS, 16 B per lane (m97 pattern). LDS dest must be the
// wave-uniform chunk base; HW adds lane*16.
__device__ __forceinline__ void gld16(const void* g, void* l)
{
    __builtin_amdgcn_global_load_lds(
        (const __attribute__((address_space(1))) void*)g,
        (__attribute__((address_space(3))) void*)l, 16, 0, 0);
}

// ===========================================================================
// CSR-by-dst build (once per call; reused by all 3 conv layers)
// ===========================================================================
constexpr int SCAN_CHUNK = 1024;
constexpr int SCAN_NBLK  = (NN + SCAN_CHUNK - 1) / SCAN_CHUNK;   // 196

__global__ __launch_bounds__(256)
void k_hist(const int* __restrict__ ei, int* __restrict__ cnt)
{
    int e = blockIdx.x * 256 + threadIdx.x;
    const int stride = gridDim.x * 256;
    for (; e < NE; e += stride) atomicAdd(&cnt[ei[NE + e]], 1);
}

__global__ __launch_bounds__(256)
void k_scan_block(const int* __restrict__ cnt, int* __restrict__ bsum)
{
    __shared__ int red[256];
    const int b = blockIdx.x, t = threadIdx.x;
    const int base = b * SCAN_CHUNK + t * 4;
    int s = 0;
    #pragma unroll
    for (int k = 0; k < 4; ++k) { const int i = base + k; if (i < NN) s += cnt[i]; }
    red[t] = s; __syncthreads();
    for (int off = 128; off > 0; off >>= 1) {
        if (t < off) red[t] += red[t + off];
        __syncthreads();
    }
    if (t == 0) bsum[b] = red[0];
}

__global__ __launch_bounds__(256)
void k_scan_top(int* __restrict__ bsum, int n)
{
    __shared__ int sh[256];
    const int t = threadIdx.x;
    const int orig = (t < n) ? bsum[t] : 0;
    sh[t] = orig; __syncthreads();
    for (int off = 1; off < 256; off <<= 1) {
        const int v = (t >= off) ? sh[t - off] : 0;
        __syncthreads();
        sh[t] += v;
        __syncthreads();
    }
    if (t < n) bsum[t] = sh[t] - orig;   // exclusive
}

__global__ __launch_bounds__(256)
void k_scan_emit(const int* __restrict__ cnt, const int* __restrict__ bsum,
                 int* __restrict__ row_ptr, int* __restrict__ cursor)
{
    __shared__ int sh[256];
    const int b = blockIdx.x, t = threadIdx.x;
    const int base = b * SCAN_CHUNK + t * 4;
    int c[4]; int s = 0;
    #pragma unroll
    for (int k = 0; k < 4; ++k) {
        const int i = base + k;
        c[k] = (i < NN) ? cnt[i] : 0;    // read BEFORE aliased write below
        s += c[k];
    }
    const int orig = s;
    sh[t] = s; __syncthreads();
    for (int off = 1; off < 256; off <<= 1) {
        const int v = (t >= off) ? sh[t - off] : 0;
        __syncthreads();
        sh[t] += v;
        __syncthreads();
    }
    int run = bsum[b] + sh[t] - orig;     // exclusive prefix of this thread
    #pragma unroll
    for (int k = 0; k < 4; ++k) {
        const int i = base + k;
        if (i < NN) { row_ptr[i] = run; cursor[i] = run; run += c[k]; }
    }
    if (b == 0 && t == 0) row_ptr[NN] = NE;
}

__global__ __launch_bounds__(256)
void k_scatter(const int* __restrict__ ei, int* __restrict__ cursor,
               int* __restrict__ perm)
{
    int e = blockIdx.x * 256 + threadIdx.x;
    const int stride = gridDim.x * 256;
    for (; e < NE; e += stride) {
        const int d = ei[NE + e];
        const int p = atomicAdd(&cursor[d], 1);
        perm[p] = e;
    }
}

// Fused-block boundaries: nb[t] = first node of block t, by binary search on
// W(n) = row_ptr[n] + n with target t*(NE+NN)/NB.
__global__ __launch_bounds__(256)
void k_bounds2(const int* __restrict__ row_ptr, int* __restrict__ nb)
{
    const int t = blockIdx.x * 256 + threadIdx.x;
    if (t > NB) return;
    const long long target = (long long)t * (NE + NN) / NB;
    int lo = 0, hi = NN;
    while (lo < hi) {
        const int mid = (lo + hi) >> 1;
        const long long W = (long long)row_ptr[mid] + mid;
        if (W >= target) hi = mid; else lo = mid + 1;
    }
    nb[t] = lo;
}

// Edge features as bf16 [NE,32] in perm order, zero-padded K 16->32.
__global__ __launch_bounds__(256)
void k_gather_edges_bf(const int* __restrict__ ei, const float* __restrict__ ea,
                       const int* __restrict__ perm, int* __restrict__ src_perm,
                       bf16* __restrict__ ea_bf)
{
    const int t = blockIdx.x * 256 + threadIdx.x;    // over NE*16 (2 bf16 each)
    if (t >= NE * 16) return;
    const int idx = t >> 4, k2 = (t & 15) * 2;       // k2 in 0..30
    const int e = perm[idx];
    union { ushort2 u; bf16 h[2]; } o;
    if (k2 < ED) {
        const float2 v = *(const float2*)&ea[(size_t)e * ED + k2];
        o.h[0] = __float2bfloat16(v.x);
        o.h[1] = __float2bfloat16(v.y);
    } else {
        o.u = make_ushort2(0, 0);
    }
    *(ushort2*)&ea_bf[(size_t)idx * 32 + k2] = o.u;
    if ((t & 15) == 0) src_perm[idx] = ei[e];
}

// One-shot: W[K,N] fp32 -> Wt[N,K] bf16 (transposed for the MFMA GEMM).
__global__ __launch_bounds__(256)
void k_wt(const float* __restrict__ W, bf16* __restrict__ Wt, int K, int N)
{
    const int i = blockIdx.x * 256 + threadIdx.x;
    if (i >= K * N) return;
    const int k = i / N, n = i % N;
    Wt[(size_t)n * K + k] = __float2bfloat16(W[i]);
}

// One-shot: We[16,cin] fp32 -> Wte[cin,32] bf16, K zero-padded 16->32.
__global__ __launch_bounds__(256)
void k_wte(const float* __restrict__ We, bf16* __restrict__ Wte, int cin)
{
    const int i = blockIdx.x * 256 + threadIdx.x;    // over cin*32
    if (i >= cin * 32) return;
    const int n = i >> 5, k = i & 31;
    Wte[i] = __float2bfloat16((k < ED) ? We[k * cin + n] : 0.f);
}

// BN fold coefficients: A = g*rsqrt(var+eps), B = beta - mu*A.
// st layout: [0..255]=sum, [256..511]=sumsq, [512..767]=A, [768..1023]=B.
__global__ __launch_bounds__(256)
void k_bnab(float* __restrict__ st, const float* __restrict__ g,
            const float* __restrict__ b)
{
    const int c = threadIdx.x;
    const float inv = 1.f / (float)NN;
    const float mu  = st[c] * inv;
    const float var = st[256 + c] * inv - mu * mu;
    const float A   = g[c] * rsqrtf(var + BN_EPS);
    st[512 + c] = A;
    st[768 + c] = b[c] - mu * A;
}

// ===========================================================================
// FUSED edge-MLP + aggregation, CIN=128 (layer 0), 512 threads / 8 waves,
// 64-edge tile.  LDS ~22 KB -> 4 blocks/CU (wave-capped) = 32 waves/CU.
// ===========================================================================
template<typename XT, bool FOLD>
__global__ __launch_bounds__(512)
void fused_agg128(const XT* __restrict__ x, const bf16* __restrict__ ea_bf,
                  const bf16* __restrict__ Wte, const float* __restrict__ be,
                  const int* __restrict__ src_perm, const int* __restrict__ row_ptr,
                  const int* __restrict__ nb, const float* __restrict__ st,
                  bf16* __restrict__ agg)
{
    constexpr int CIN  = 128;
    constexpr int MSTR = CIN + 8;                  // msg LDS row stride (bf16)
    constexpr int CPL  = 2;                        // channels per lane
    __shared__ short ea_s[EMAX * 32];              // 4 KB
    __shared__ short msg[EMAX * MSTR];             // 17.4 KB
    __shared__ int   src_lds[EMAX];
    __shared__ int   rp_lds[EMAX + 4];

    const int tid  = threadIdx.x;
    const int lane = tid & 63;
    const int wv   = tid >> 6;                     // 0..7
    const int b    = blockIdx.x;
    const int n0 = nb[b], n1 = nb[b + 1];
    if (n0 >= n1) return;
    const int e0 = row_ptr[n0];
    const int e1 = row_ptr[n1];
    int ne = e1 - e0; if (ne > EMAX) ne = EMAX;    // insurance clamp
    int nnb = n1 - n0; if (nnb > EMAX) nnb = EMAX; // insurance clamp

    const int l15  = lane & 15;
    const int quad = lane >> 4;
    const int rsub = lane >> 2;
    const int part = lane & 3;

    // ---- stage ea rows (waves 0-3, 16 rows each) ----
    if (wv < 4) {
        int r = wv * 16 + rsub;
        if (r >= ne) r = ne - 1;
        gld16(&ea_bf[(size_t)(e0 + r) * 32 + part * 8], &ea_s[wv * 512]);
    }
    // ---- stage src + row_ptr slices (contiguous; overlaps with gld16) ----
    if (tid >= 256 && tid < 320) {
        const int i = tid - 256;
        src_lds[i] = src_perm[e0 + ((i < ne) ? i : ne - 1)];
    } else if (tid >= 320 && tid < 448) {
        const int i = tid - 320;
        if (i <= nnb) rp_lds[i] = row_ptr[n0 + i];
    }

    // ---- Wte fragments + bias: wave strip (wr=16-row, wc=64-col) ----
    const int wc = (wv & 1) * 64;
    const int wr = (wv >> 1) * 16;
    bf16x8 bfr[4];
    #pragma unroll
    for (int i = 0; i < 4; ++i)
        bfr[i] = *(const bf16x8*)&Wte[(size_t)(wc + i * 16 + l15) * 32 + quad * 8];
    float bv[4];
    #pragma unroll
    for (int ni = 0; ni < 4; ++ni)
        bv[ni] = be[wc + ni * 16 + l15];

    __syncthreads();                               // ea + src + rp staged

    // ---- phase 1: MFMA edge-MLP -> msg LDS (4 MFMA per wave) ----
    {
        f32x4 acc[4];
        #pragma unroll
        for (int j = 0; j < 4; ++j)
            acc[j] = (f32x4){0.f, 0.f, 0.f, 0.f};
        const bf16x8 af = *(const bf16x8*)&ea_s[(wr + l15) * 32 + quad * 8];
        #pragma unroll
        for (int ni = 0; ni < 4; ++ni)
            acc[ni] = __builtin_amdgcn_mfma_f32_16x16x32_bf16(
                          af, bfr[ni], acc[ni], 0, 0, 0);
        const int row0 = wr + quad * 4;
        #pragma unroll
        for (int r = 0; r < 4; ++r) {
            const int row = row0 + r;
            #pragma unroll
            for (int ni = 0; ni < 4; ++ni) {
                const float v = acc[ni][r] + bv[ni];
                msg[row * MSTR + wc + ni * 16 + l15] =
                    (short)__bfloat16_as_ushort(__float2bfloat16(v));
            }
        }
    }
    __syncthreads();                               // msg ready

    // ---- phase 2: node-major aggregation, 8-wave stride ----
    const int c0 = lane * CPL;
    float Af[CPL], Bf[CPL];
    #pragma unroll
    for (int q = 0; q < CPL; ++q) {
        Af[q] = FOLD ? st[512 + c0 + q] : 1.f;
        Bf[q] = FOLD ? st[768 + c0 + q] : 0.f;
    }

    for (int ni = wv; ni < nnb; ni += 8) {
        const int node = n0 + ni;
        float acc2[CPL];
        const float2 v = ld2f(&x[(size_t)node * CIN + c0]);
        acc2[0] = fmaf(v.x, Af[0], Bf[0]);
        acc2[1] = fmaf(v.y, Af[1], Bf[1]);

        const int f0 = rp_lds[ni], f1 = rp_lds[ni + 1];
        for (int base2 = f0; base2 < f1; base2 += 8) {
            float2 xv[8]; ushort2 mv[8];
            #pragma unroll
            for (int j = 0; j < 8; ++j) {
                int idx = base2 + j; if (idx >= f1) idx = f1 - 1;
                int l = idx - e0; if (l > EMAX - 1) l = EMAX - 1;
                const int sv = src_lds[l];
                xv[j] = ld2f(&x[(size_t)sv * CIN + c0]);
                mv[j] = *(const ushort2*)&msg[l * MSTR + c0];
            }
            #pragma unroll
            for (int j = 0; j < 8; ++j) {
                if (base2 + j < f1) {
                    acc2[0] += fmaxf(fmaf(xv[j].x, Af[0], Bf[0]) + bfraw(mv[j].x), 0.f);
                    acc2[1] += fmaxf(fmaf(xv[j].y, Af[1], Bf[1]) + bfraw(mv[j].y), 0.f);
                }
            }
        }

        union { ushort2 u; bf16 h[2]; } t;
        t.h[0] = __float2bfloat16(acc2[0]);
        t.h[1] = __float2bfloat16(acc2[1]);
        *(ushort2*)&agg[(size_t)node * CIN + c0] = t.u;
    }
}

// ===========================================================================
// FUSED edge-MLP + aggregation, CIN=256 (layers 1,2): 512 threads / 8 waves,
// 64-edge tile.  LDS ~38 KB -> 4 blocks/CU = 32 waves/CU.
// ===========================================================================
template<bool FOLD>
__global__ __launch_bounds__(512)
void fused_agg256(const bf16* __restrict__ x, const bf16* __restrict__ ea_bf,
                  const bf16* __restrict__ Wte, const float* __restrict__ be,
                  const int* __restrict__ src_perm, const int* __restrict__ row_ptr,
                  const int* __restrict__ nb, const float* __restrict__ st,
                  bf16* __restrict__ agg)
{
    constexpr int CIN  = 256;
    constexpr int MSTR = CIN + 8;                  // msg LDS row stride (bf16)
    constexpr int CPL  = 4;
    __shared__ short ea_s[EMAX * 32];              // 4 KB
    __shared__ short msg[EMAX * MSTR];             // 33.8 KB
    __shared__ int   src_lds[EMAX];
    __shared__ int   rp_lds[EMAX + 4];

    const int tid  = threadIdx.x;
    const int lane = tid & 63;
    const int wv   = tid >> 6;                     // 0..7
    const int b    = blockIdx.x;
    const int n0 = nb[b], n1 = nb[b + 1];
    if (n0 >= n1) return;
    const int e0 = row_ptr[n0];
    const int e1 = row_ptr[n1];
    int ne = e1 - e0; if (ne > EMAX) ne = EMAX;    // insurance clamp
    int nnb = n1 - n0; if (nnb > EMAX) nnb = EMAX; // insurance clamp

    const int l15  = lane & 15;
    const int quad = lane >> 4;
    const int rsub = lane >> 2;
    const int part = lane & 3;

    // ---- stage ea rows (waves 0-3, 16 rows each) ----
    if (wv < 4) {
        int r = wv * 16 + rsub;
        if (r >= ne) r = ne - 1;
        gld16(&ea_bf[(size_t)(e0 + r) * 32 + part * 8], &ea_s[wv * 512]);
    }
    // ---- stage src + row_ptr slices (contiguous; overlaps with gld16) ----
    if (tid >= 256 && tid < 320) {
        const int i = tid - 256;
        src_lds[i] = src_perm[e0 + ((i < ne) ? i : ne - 1)];
    } else if (tid >= 320 && tid < 448) {
        const int i = tid - 320;
        if (i <= nnb) rp_lds[i] = row_ptr[n0 + i];
    }

    // ---- Wte fragments + bias: wave quadrant (wr=32-row, wc=64-col) ----
    const int wc = (wv & 3) * 64;
    const int wr = (wv >> 2) * 32;
    bf16x8 bfr[4];
    #pragma unroll
    for (int i = 0; i < 4; ++i)
        bfr[i] = *(const bf16x8*)&Wte[(size_t)(wc + i * 16 + l15) * 32 + quad * 8];
    float bv[4];
    #pragma unroll
    for (int ni = 0; ni < 4; ++ni)
        bv[ni] = be[wc + ni * 16 + l15];

    __syncthreads();                               // ea + src + rp staged

    // ---- phase 1: MFMA edge-MLP -> msg LDS (8 MFMA per wave) ----
    {
        f32x4 acc[2][4];
        #pragma unroll
        for (int i = 0; i < 2; ++i)
            #pragma unroll
            for (int j = 0; j < 4; ++j)
                acc[i][j] = (f32x4){0.f, 0.f, 0.f, 0.f};
        bf16x8 af[2];
        #pragma unroll
        for (int i = 0; i < 2; ++i)
            af[i] = *(const bf16x8*)&ea_s[(wr + i * 16 + l15) * 32 + quad * 8];
        #pragma unroll
        for (int mi = 0; mi < 2; ++mi)
            #pragma unroll
            for (int ni = 0; ni < 4; ++ni)
                acc[mi][ni] = __builtin_amdgcn_mfma_f32_16x16x32_bf16(
                                  af[mi], bfr[ni], acc[mi][ni], 0, 0, 0);
        #pragma unroll
        for (int mi = 0; mi < 2; ++mi) {
            const int row0 = wr + mi * 16 + quad * 4;
            #pragma unroll
            for (int r = 0; r < 4; ++r) {
                const int row = row0 + r;
                #pragma unroll
                for (int ni = 0; ni < 4; ++ni) {
                    const float v = acc[mi][ni][r] + bv[ni];
                    msg[row * MSTR + wc + ni * 16 + l15] =
                        (short)__bfloat16_as_ushort(__float2bfloat16(v));
                }
            }
        }
    }
    __syncthreads();                               // msg ready

    // ---- phase 2: node-major aggregation, 8-wave stride ----
    const int c0 = lane * CPL;
    float Af[CPL], Bf[CPL];
    #pragma unroll
    for (int q = 0; q < CPL; ++q) {
        Af[q] = FOLD ? st[512 + c0 + q] : 1.f;
        Bf[q] = FOLD ? st[768 + c0 + q] : 0.f;
    }

    for (int ni = wv; ni < nnb; ni += 8) {
        const int node = n0 + ni;
        float acc2[CPL];
        const float4 v = ld4(&x[(size_t)node * CIN + c0]);
        acc2[0] = fmaf(v.x, Af[0], Bf[0]); acc2[1] = fmaf(v.y, Af[1], Bf[1]);
        acc2[2] = fmaf(v.z, Af[2], Bf[2]); acc2[3] = fmaf(v.w, Af[3], Bf[3]);

        const int f0 = rp_lds[ni], f1 = rp_lds[ni + 1];
        for (int base2 = f0; base2 < f1; base2 += 8) {
            ushort4 xr[8]; ushort4 mv[8];
            #pragma unroll
            for (int j = 0; j < 8; ++j) {
                int idx = base2 + j; if (idx >= f1) idx = f1 - 1;
                int l = idx - e0; if (l > EMAX - 1) l = EMAX - 1;
                const int sv = src_lds[l];
                xr[j] = *(const ushort4*)&x[(size_t)sv * CIN + c0];
                mv[j] = *(const ushort4*)&msg[l * MSTR + c0];
            }
            #pragma unroll
            for (int j = 0; j < 8; ++j) {
                if (base2 + j < f1) {
                    acc2[0] += fmaxf(fmaf(bfraw(xr[j].x), Af[0], Bf[0]) + bfraw(mv[j].x), 0.f);
                    acc2[1] += fmaxf(fmaf(bfraw(xr[j].y), Af[1], Bf[1]) + bfraw(mv[j].y), 0.f);
                    acc2[2] += fmaxf(fmaf(bfraw(xr[j].z), Af[2], Bf[2]) + bfraw(mv[j].z), 0.f);
                    acc2[3] += fmaxf(fmaf(bfraw(xr[j].w), Af[3], Bf[3]) + bfraw(mv[j].w), 0.f);
                }
            }
        }

        union { ushort4 u; bf16 h[4]; } t;
        t.h[0] = __float2bfloat16(acc2[0]); t.h[1] = __float2bfloat16(acc2[1]);
        t.h[2] = __float2bfloat16(acc2[2]); t.h[3] = __float2bfloat16(acc2[3]);
        *(ushort4*)&agg[(size_t)node * CIN + c0] = t.u;
    }
}

// ===========================================================================
// Conv MFMA GEMM: C[M,256] = relu(A[M,K] @ Wt[256,K]^T + bias), bf16 out.
// m97-style global_load_lds staging (linear [128][32] LDS, 16 B/lane).
// MINW = min waves/SIMD for launch_bounds.  MINW=3 verified (64 VGPR + 64
// AGPR = 128 regs, no spill).  MINW=4 is the A/B probe: budget is exactly
// 128 regs -- fits iff the allocator needs nothing extra.  MINW=6 spilled
// the accumulators (round 8: 4x traffic) -- never use.
// STATS: per-channel sum/sumsq of post-relu output into st (quad-reduce).
// ===========================================================================
template<int K, bool STATS, int MINW>
__global__ __launch_bounds__(256, MINW)
void gemm_mfma(const bf16* __restrict__ A, const bf16* __restrict__ Wt,
               const float* __restrict__ bias, bf16* __restrict__ C, int M,
               float* __restrict__ st)
{
    __shared__ short As[128 * 32];   // 8 KB, linear
    __shared__ short Bs[128 * 32];
    const int tid  = threadIdx.x;
    const int bm   = blockIdx.y * 128;
    const int bn   = blockIdx.x * 128;      // 0 or 128 (N = 256)
    const int lane = tid & 63;
    const int wave = tid >> 6;
    const int wr   = (wave >> 1) * 64;
    const int wc   = (wave & 1) * 64;
    const int l15  = lane & 15;
    const int quad = lane >> 4;
    const int rsub = lane >> 2;
    const int part = lane & 3;

    f32x4 acc[4][4];
    #pragma unroll
    for (int i = 0; i < 4; ++i)
        #pragma unroll
        for (int j = 0; j < 4; ++j)
            acc[i][j] = (f32x4){0.f, 0.f, 0.f, 0.f};

    for (int k0 = 0; k0 < K; k0 += 32) {
        #pragma unroll
        for (int i = 0; i < 2; ++i) {
            const int ca = wave * 2 + i;
            int ar = bm + ca * 16 + rsub; if (ar >= M) ar = M - 1;
            gld16(&A[(size_t)ar * K + k0 + part * 8], &As[ca * 512]);
            gld16(&Wt[(size_t)(bn + ca * 16 + rsub) * K + k0 + part * 8],
                  &Bs[ca * 512]);
        }
        __syncthreads();

        bf16x8 af[4], bfr[4];
        #pragma unroll
        for (int i = 0; i < 4; ++i) {
            af[i]  = *(const bf16x8*)&As[(wr + i * 16 + l15) * 32 + quad * 8];
            bfr[i] = *(const bf16x8*)&Bs[(wc + i * 16 + l15) * 32 + quad * 8];
        }
        #pragma unroll
        for (int mi = 0; mi < 4; ++mi)
            #pragma unroll
            for (int ni = 0; ni < 4; ++ni)
                acc[mi][ni] = __builtin_amdgcn_mfma_f32_16x16x32_bf16(
                                  af[mi], bfr[ni], acc[mi][ni], 0, 0, 0);
        __syncthreads();
    }

    float bv[4];
    #pragma unroll
    for (int ni = 0; ni < 4; ++ni)
        bv[ni] = bias[bn + wc + ni * 16 + l15];
    float ps[4]  = {0.f, 0.f, 0.f, 0.f};
    float ps2[4] = {0.f, 0.f, 0.f, 0.f};
    #pragma unroll
    for (int mi = 0; mi < 4; ++mi) {
        const int row0 = bm + wr + mi * 16 + quad * 4;
        #pragma unroll
        for (int r = 0; r < 4; ++r) {
            const int row = row0 + r;
            if (row < M) {
                #pragma unroll
                for (int ni = 0; ni < 4; ++ni) {
                    float v = acc[mi][ni][r] + bv[ni];
                    v = fmaxf(v, 0.f);
                    C[(size_t)row * 256 + bn + wc + ni * 16 + l15] = __float2bfloat16(v);
                    if (STATS) { ps[ni] += v; ps2[ni] = fmaf(v, v, ps2[ni]); }
                }
            }
        }
    }
    if (STATS) {
        #pragma unroll
        for (int ni = 0; ni < 4; ++ni) {
            float s = ps[ni], q = ps2[ni];
            s += __shfl_xor(s, 16); s += __shfl_xor(s, 32);
            q += __shfl_xor(q, 16); q += __shfl_xor(q, 32);
            if (quad == 0) {
                const int col = bn + wc + ni * 16 + l15;
                atomicAdd(&st[col], s);
                atomicAdd(&st[256 + col], q);
            }
        }
    }
}

// ---------------------------------------------------------------------------
// fp32 GEMM (dense head only): C = (relu?)(A @ W + bias)
// ---------------------------------------------------------------------------
template<bool RELU, typename InT, typename OutT>
__global__ __launch_bounds__(256)
void gemm_rk(const InT* __restrict__ A, const float* __restrict__ W,
             const float* __restrict__ bias, OutT* __restrict__ C,
             int M, int N, int K)
{
    __shared__ float Asm[16][64];
    __shared__ float Wsm[16][64];
    const int bm = blockIdx.y * 64;
    const int bn = blockIdx.x * 64;
    const int tid = threadIdx.x;
    const int tx = tid & 15, ty = tid >> 4;
    const int ar = tid >> 2, ac = (tid & 3) * 4;
    const int wrr = tid >> 4, wcc = (tid & 15) * 4;

    float acc[4][4] = {};

    for (int k0 = 0; k0 < K; k0 += 16) {
        float4 av = make_float4(0.f, 0.f, 0.f, 0.f);
        if (bm + ar < M)
            av = ld4(A + (size_t)(bm + ar) * K + k0 + ac);
        Asm[ac + 0][ar] = av.x; Asm[ac + 1][ar] = av.y;
        Asm[ac + 2][ar] = av.z; Asm[ac + 3][ar] = av.w;

        float4 wv = make_float4(0.f, 0.f, 0.f, 0.f);
        if (bn + wcc < N)
            wv = *(const float4*)(W + (size_t)(k0 + wrr) * N + bn + wcc);
        *(float4*)&Wsm[wrr][wcc] = wv;
        __syncthreads();

        #pragma unroll
        for (int k = 0; k < 16; ++k) {
            const float4 a4 = *(const float4*)&Asm[k][ty * 4];
            const float4 b4 = *(const float4*)&Wsm[k][tx * 4];
            const float aa[4] = {a4.x, a4.y, a4.z, a4.w};
            const float bb[4] = {b4.x, b4.y, b4.z, b4.w};
            #pragma unroll
            for (int i = 0; i < 4; ++i)
                #pragma unroll
                for (int j = 0; j < 4; ++j)
                    acc[i][j] += aa[i] * bb[j];
        }
        __syncthreads();
    }

    float bvals[4];
    #pragma unroll
    for (int j = 0; j < 4; ++j) {
        const int col = bn + tx * 4 + j;
        bvals[j] = (col < N) ? bias[col] : 0.f;
    }
    #pragma unroll
    for (int i = 0; i < 4; ++i) {
        const int row = bm + ty * 4 + i;
        if (row >= M) continue;
        float v[4];
        #pragma unroll
        for (int j = 0; j < 4; ++j) {
            v[j] = acc[i][j] + bvals[j];
            if (RELU) v[j] = fmaxf(v[j], 0.f);
        }
        if (bn + tx * 4 + 3 < N) {
            st4(C + (size_t)row * N + bn + tx * 4, make_float4(v[0], v[1], v[2], v[3]));
        } else {
            #pragma unroll
            for (int j = 0; j < 4; ++j) {
                const int col = bn + tx * 4 + j;
                if (col < N) st1(C + (size_t)row * N + col, v[j]);
            }
        }
    }
}

// ---------------------------------------------------------------------------
// Mean-pool over sorted batch ids, with BN fold applied on the fly.
// ---------------------------------------------------------------------------
template<typename InT, bool FOLD>
__global__ __launch_bounds__(256)
void pool_sum(const InT* __restrict__ h, const int* __restrict__ batch,
              const float* __restrict__ st,
              float* __restrict__ sums, float* __restrict__ cnts)
{
    const int c = threadIdx.x;
    size_t n0 = (size_t)blockIdx.x * 128;
    size_t n1 = n0 + 128; if (n1 > (size_t)NN) n1 = NN;
    if (n0 >= (size_t)NN) return;
    const float A = FOLD ? st[512 + c] : 1.f;
    const float B = FOLD ? st[768 + c] : 0.f;
    int cur = batch[n0];
    float s = 0.f, cnt = 0.f;
    for (size_t n = n0; n < n1; ++n) {
        const int b = batch[n];
        if (b != cur) {
            atomicAdd(&sums[(size_t)cur * 256 + c], s);
            if (c == 0) atomicAdd(&cnts[cur], cnt);
            s = 0.f; cnt = 0.f; cur = b;
        }
        const float v = ld1(&h[n * 256 + c]);
        s += fmaf(v, A, B);
        cnt += 1.f;
    }
    atomicAdd(&sums[(size_t)cur * 256 + c], s);
    if (c == 0) atomicAdd(&cnts[cur], cnt);
}

__global__ __launch_bounds__(256)
void pool_div(float* __restrict__ sums, const float* __restrict__ cnts)
{
    const int i = blockIdx.x * 256 + threadIdx.x;   // NG*256 threads exactly
    const int g = i >> 8;
    sums[i] = sums[i] / fmaxf(cnts[g], 1.f);
}

__global__ __launch_bounds__(256)
void head_out(const float* __restrict__ y, const float* __restrict__ Wo,
              const float* __restrict__ bo, float* __restrict__ out)
{
    const int g = blockIdx.x * 256 + threadIdx.x;
    if (g >= NG) return;
    float s = bo[0];
    #pragma unroll
    for (int k = 0; k < 32; ++k) s += y[g * 32 + k] * Wo[k];
    out[g] = s;
}

__global__ __launch_bounds__(256)
void diag_fill(float* __restrict__ out, int n, float v)
{
    const int i = blockIdx.x * 256 + threadIdx.x;
    if (i < n) out[i] = v;
}

// ---------------------------------------------------------------------------
extern "C" void kernel_launch(void* const* d_in, const int* in_sizes, int n_in,
                              void* d_out, int out_size, void* d_ws, size_t ws_size,
                              hipStream_t stream)
{
    const float* x    = (const float*)d_in[0];
    const int*   ei   = (const int*)d_in[1];
    const int*   batch= (const int*)d_in[2];
    const float* ea   = (const float*)d_in[3];
    const float* We[3] = {(const float*)d_in[4],  (const float*)d_in[10], (const float*)d_in[16]};
    const float* be[3] = {(const float*)d_in[5],  (const float*)d_in[11], (const float*)d_in[17]};
    const float* Wn[3] = {(const float*)d_in[6],  (const float*)d_in[12], (const float*)d_in[18]};
    const float* bnb[3]= {(const float*)d_in[7],  (const float*)d_in[13], (const float*)d_in[19]};
    const float* gm[3] = {(const float*)d_in[8],  (const float*)d_in[14], (const float*)d_in[20]};
    const float* bt[3] = {(const float*)d_in[9],  (const float*)d_in[15], (const float*)d_in[21]};
    const float* Wd0 = (const float*)d_in[22]; const float* bd0 = (const float*)d_in[23];
    const float* Wd1 = (const float*)d_in[24]; const float* bd1 = (const float*)d_in[25];
    const float* Wd2 = (const float*)d_in[26]; const float* bd2 = (const float*)d_in[27];
    const float* Wo  = (const float*)d_in[28]; const float* bo  = (const float*)d_in[29];
    float* out = (float*)d_out;
    float* ws  = (float*)d_ws;

    // ---- workspace layout (float offsets; 16B alignment kept) ----
    constexpr size_t OFF_H    = 0;                            // NN*256 bf16
    constexpr size_t OFF_AGG  = 25600000;                     // NN*256 bf16
    constexpr size_t OFF_ST   = 51200000;                     // 1536 fl
    constexpr size_t OFF_WT0  = OFF_ST + 1536;                // 128*256 bf16
    constexpr size_t OFF_WT1  = OFF_WT0 + 16384;              // 256*256 bf16
    constexpr size_t OFF_WT2  = OFF_WT1 + 32768;              // 256*256 bf16
    constexpr size_t OFF_WTE0 = OFF_WT2 + 32768;              // 128*32 bf16
    constexpr size_t OFF_WTE1 = OFF_WTE0 + 2048;              // 256*32 bf16
    constexpr size_t OFF_WTE2 = OFF_WTE1 + 4096;              // 256*32 bf16
    constexpr size_t OFF_EA   = OFF_WTE2 + 4096;              // NE*32 bf16
    constexpr size_t OFF_SRC  = OFF_EA + 12800000;            // NE int
    constexpr size_t OFF_RP   = OFF_SRC + NE;                 // NN+1 int
    constexpr size_t OFF_CUR  = OFF_RP + (NN + 1);            // NN int
    constexpr size_t OFF_PERM = OFF_CUR + NN;                 // NE int
    constexpr size_t OFF_BSUM = OFF_PERM + NE;                // SCAN_NBLK int
    constexpr size_t OFF_NB   = OFF_BSUM + SCAN_NBLK;         // NB+1 int
    constexpr size_t BASE_END = OFF_NB + (NB + 4);
    constexpr size_t NEED_BASE = BASE_END * 4;

    bf16*  H        = (bf16*)(ws + OFF_H);
    bf16*  AGG      = (bf16*)(ws + OFF_AGG);
    float* st       = ws + OFF_ST;
    bf16*  wt0      = (bf16*)(ws + OFF_WT0);
    bf16*  wt1      = (bf16*)(ws + OFF_WT1);
    bf16*  wt2      = (bf16*)(ws + OFF_WT2);
    bf16*  wte[3]   = {(bf16*)(ws + OFF_WTE0), (bf16*)(ws + OFF_WTE1), (bf16*)(ws + OFF_WTE2)};
    bf16*  ea_bf    = (bf16*)(ws + OFF_EA);
    int*   src_perm = (int*)(ws + OFF_SRC);
    int*   row_ptr  = (int*)(ws + OFF_RP);
    int*   cursor   = (int*)(ws + OFF_CUR);
    int*   perm     = (int*)(ws + OFF_PERM);
    int*   bsum     = (int*)(ws + OFF_BSUM);
    int*   nb       = (int*)(ws + OFF_NB);

    if (ws_size < NEED_BASE) {
        diag_fill<<<(NG + 255) / 256, 256, 0, stream>>>(out, NG, (float)(ws_size >> 20));
        return;
    }

    // ---- one-time prep: CSR build, edge pre-gather, weight transpose ----
    hipMemsetAsync(row_ptr, 0, (size_t)(NN + 1) * 4, stream);
    k_hist<<<1024, 256, 0, stream>>>(ei, row_ptr);
    k_scan_block<<<SCAN_NBLK, 256, 0, stream>>>(row_ptr, bsum);
    k_scan_top<<<1, 256, 0, stream>>>(bsum, SCAN_NBLK);
    k_scan_emit<<<SCAN_NBLK, 256, 0, stream>>>(row_ptr, bsum, row_ptr, cursor);
    k_scatter<<<1024, 256, 0, stream>>>(ei, cursor, perm);
    k_bounds2<<<(NB + 256) / 256, 256, 0, stream>>>(row_ptr, nb);
    k_gather_edges_bf<<<(NE * 16 + 255) / 256, 256, 0, stream>>>(ei, ea, perm, src_perm, ea_bf);
    k_wte<<<(128 * 32 + 255) / 256, 256, 0, stream>>>(We[0], wte[0], 128);
    k_wte<<<(256 * 32 + 255) / 256, 256, 0, stream>>>(We[1], wte[1], 256);
    k_wte<<<(256 * 32 + 255) / 256, 256, 0, stream>>>(We[2], wte[2], 256);
    k_wt<<<(128 * 256 + 255) / 256, 256, 0, stream>>>(Wn[0], wt0, 128, 256);
    k_wt<<<(256 * 256 + 255) / 256, 256, 0, stream>>>(Wn[1], wt1, 256, 256);
    k_wt<<<(256 * 256 + 255) / 256, 256, 0, stream>>>(Wn[2], wt2, 256, 256);

    const dim3 mfma_grid(2, (NN + 127) / 128);    // conv GEMMs: N=256

    // ---- layer 0 (cin=128 -> 256), input x fp32, no fold ----
    fused_agg128<float, false><<<NB, 512, 0, stream>>>(
        x, ea_bf, wte[0], be[0], src_perm, row_ptr, nb, st, AGG);
    hipMemsetAsync(st, 0, 512 * 4, stream);
    // A/B probe: MINW=4 on the K=128 conv only (budget exactly 128 regs).
    gemm_mfma<128, true, 4><<<mfma_grid, 256, 0, stream>>>(AGG, wt0, bnb[0], H, NN, st);
    k_bnab<<<1, 256, 0, stream>>>(st, gm[0], bt[0]);

    // ---- layers 1,2 (256 -> 256), input H bf16 raw + fold(A,B) ----
    for (int l = 1; l < 3; ++l) {
        fused_agg256<true><<<NB, 512, 0, stream>>>(
            H, ea_bf, wte[l], be[l], src_perm, row_ptr, nb, st, AGG);
        hipMemsetAsync(st, 0, 512 * 4, stream);
        gemm_mfma<256, true, 3><<<mfma_grid, 256, 0, stream>>>(
            AGG, (l == 1) ? wt1 : wt2, bnb[l], H, NN, st);
        k_bnab<<<1, 256, 0, stream>>>(st, gm[l], bt[l]);
    }

    // ---- head scratch overlays AGG (dead after last conv GEMM) ----
    float* poolb = (float*)AGG;           // NG*256 = 1,024,000 fl
    float* cnts  = poolb + 1024000;       // NG
    float* y1    = poolb + 1028000;       // NG*512
    float* y2    = poolb + 3076000;       // NG*128
    float* y3    = poolb + 3588000;       // NG*32

    hipMemsetAsync(poolb, 0, (size_t)NG * 256 * 4, stream);
    hipMemsetAsync(cnts, 0, (size_t)NG * 4, stream);
    pool_sum<bf16, true><<<(NN + 127) / 128, 256, 0, stream>>>(H, batch, st, poolb, cnts);
    pool_div<<<NG, 256, 0, stream>>>(poolb, cnts);

    // ---- dense head (fp32) ----
    gemm_rk<true, float, float><<<dim3(8, (NG + 63) / 64), 256, 0, stream>>>(poolb, Wd0, bd0, y1, NG, 512, 256);
    gemm_rk<true, float, float><<<dim3(2, (NG + 63) / 64), 256, 0, stream>>>(y1, Wd1, bd1, y2, NG, 128, 512);
    gemm_rk<true, float, float><<<dim3(1, (NG + 63) / 64), 256, 0, stream>>>(y2, Wd2, bd2, y3, NG, 32, 128);
    head_out<<<(NG + 255) / 256, 256, 0, stream>>>(y3, Wo, bo, out);
}